// Round 11
// baseline (179.939 us; speedup 1.0000x reference)
//
#include <hip/hip_runtime.h>
#include <math.h>

#define BB 256
#define DD 5120
#define NN 16
#define RR 160
#define CT 192          // 160 (t) + 16 (Bm) + 16 (Cm)
#define NSPLIT 32
#define DTSPLIT 4       // k-splits for the dt GEMM (4 * 40 = 160)
#define TMP_ELEMS (BB * CT)          // 49152
#define NEGA_ELEMS (DD * NN)         // 81920

// ---------------- K1: partials[s][b][c] = x[b, ks:ks+160] @ Wcat[ks:ks+160, c]
// grid: (3 c-tiles, 4 b-tiles, 32 k-splits), block 256. (Exact r9 version.)
__global__ __launch_bounds__(256) void k1_gemm(const float* __restrict__ x,
                                               const float* __restrict__ Wxdt,
                                               const float* __restrict__ Wbc,
                                               float* __restrict__ part) {
    __shared__ float xs[32][68];   // [k][b] transposed (68: b128-aligned rows)
    __shared__ float ws[32][64];   // [k][c]
    const int tid = threadIdx.x;
    const int tx = tid & 15, ty = tid >> 4;
    const int c0 = blockIdx.x * 64;
    const int b0 = blockIdx.y * 64;
    const int k0 = blockIdx.z * 160;
    float acc[4][4] = {};

    for (int kc = 0; kc < 160; kc += 32) {
        {
            const int i  = tid >> 3;          // 0..31
            const int j4 = (tid & 7) * 4;     // 0..28
            #pragma unroll
            for (int rep = 0; rep < 2; ++rep) {
                const int row = i + rep * 32;
                const float4 v = *(const float4*)&x[(size_t)(b0 + row) * DD + k0 + kc + j4];
                xs[j4 + 0][row] = v.x;
                xs[j4 + 1][row] = v.y;
                xs[j4 + 2][row] = v.z;
                xs[j4 + 3][row] = v.w;
            }
        }
        {
            const int c4 = (tid & 15) * 4;
            const int r0 = tid >> 4;          // 0..15
            #pragma unroll
            for (int rep = 0; rep < 2; ++rep) {
                const int r  = r0 + rep * 16;
                const int kg = k0 + kc + r;
                const int cg = c0 + c4;
                float4 v;
                if (cg < RR) v = *(const float4*)&Wxdt[(size_t)kg * RR + cg];
                else         v = *(const float4*)&Wbc[(size_t)kg * 32 + (cg - RR)];
                *(float4*)&ws[r][c4] = v;
            }
        }
        __syncthreads();
        #pragma unroll
        for (int k = 0; k < 32; ++k) {
            const float4 a4 = *(const float4*)&xs[k][ty * 4];
            const float4 w4 = *(const float4*)&ws[k][tx * 4];
            const float av[4] = {a4.x, a4.y, a4.z, a4.w};
            const float wv[4] = {w4.x, w4.y, w4.z, w4.w};
            #pragma unroll
            for (int u = 0; u < 4; ++u)
                #pragma unroll
                for (int v = 0; v < 4; ++v)
                    acc[u][v] = fmaf(av[u], wv[v], acc[u][v]);
        }
        __syncthreads();
    }

    float* p = part + (size_t)blockIdx.z * TMP_ELEMS;
    #pragma unroll
    for (int u = 0; u < 4; ++u) {
        const int b = b0 + ty * 4 + u;
        *(float4*)&p[b * CT + c0 + tx * 4] =
            make_float4(acc[u][0], acc[u][1], acc[u][2], acc[u][3]);
    }
}

// ---------------- K_RED: tmp = sum_s partials; negA = -exp(A_log) -----------
__global__ __launch_bounds__(256) void k_red(const float* __restrict__ part,
                                             const float* __restrict__ Alog,
                                             float* __restrict__ tmp,
                                             float* __restrict__ negA) {
    const int idx = blockIdx.x * 256 + threadIdx.x;
    if (idx < TMP_ELEMS) {
        float s = 0.f;
        #pragma unroll
        for (int z = 0; z < NSPLIT; ++z) s += part[(size_t)z * TMP_ELEMS + idx];
        tmp[idx] = s;
    } else {
        const int j = idx - TMP_ELEMS;
        negA[j] = -__expf(Alog[j]);
    }
}

// ---------------- K_DT: dtp[s][b][d] = t[b, 40s:40s+40] @ Wdt[40s:40s+40, d]
// Clone of k1's proven tile structure: 64d x 64b x 40k per block, one stage +
// one barrier + 640-FMA loop. grid (80 d-tiles, 4 b-tiles, 4 k-splits) = 1280
// blocks (5 blocks/CU). Kills the per-thread 160-deep serial-K chain.
__global__ __launch_bounds__(256) void k_dt(const float* __restrict__ tmp,
                                            const float* __restrict__ Wdt,
                                            float* __restrict__ dtp) {
    __shared__ float ts[40][68];   // [k][b] transposed
    __shared__ float ws[40][64];   // [k][d]
    const int tid = threadIdx.x;
    const int tx = tid & 15, ty = tid >> 4;
    const int d0 = blockIdx.x * 64;
    const int b0 = blockIdx.y * 64;
    const int k0 = blockIdx.z * 40;

    // stage t tile transposed: 64 b-rows x 40 k = 640 float4 (10 per row)
    for (int p = tid; p < 640; p += 256) {
        const int row = p / 10;
        const int j4  = (p % 10) * 4;
        const float4 v = *(const float4*)&tmp[(size_t)(b0 + row) * CT + k0 + j4];
        ts[j4 + 0][row] = v.x; ts[j4 + 1][row] = v.y;
        ts[j4 + 2][row] = v.z; ts[j4 + 3][row] = v.w;
    }
    // stage Wdt tile: 40 k-rows x 64 d = 640 float4 (16 per row)
    for (int p = tid; p < 640; p += 256) {
        const int r  = p >> 4;
        const int c4 = (p & 15) * 4;
        *(float4*)&ws[r][c4] = *(const float4*)&Wdt[(size_t)(k0 + r) * DD + d0 + c4];
    }
    __syncthreads();

    float acc[4][4] = {};
    #pragma unroll 8
    for (int k = 0; k < 40; ++k) {
        const float4 a4 = *(const float4*)&ts[k][ty * 4];
        const float4 w4 = *(const float4*)&ws[k][tx * 4];
        const float av[4] = {a4.x, a4.y, a4.z, a4.w};
        const float wv[4] = {w4.x, w4.y, w4.z, w4.w};
        #pragma unroll
        for (int u = 0; u < 4; ++u)
            #pragma unroll
            for (int v = 0; v < 4; ++v)
                acc[u][v] = fmaf(av[u], wv[v], acc[u][v]);
    }

    float* p = dtp + (size_t)blockIdx.z * BB * DD;
    #pragma unroll
    for (int u = 0; u < 4; ++u) {
        const int b = b0 + ty * 4 + u;
        *(float4*)&p[(size_t)b * DD + d0 + tx * 4] =
            make_float4(acc[u][0], acc[u][1], acc[u][2], acc[u][3]);
    }
}

// ---------------- K_EPI: fully-coalesced SSM stream -------------------------
// Quad-of-lanes per (b,d) cell: lane q owns n in [4q, 4q+4). All h0/negA
// reads are contiguous 1KB-per-wave vmem ops (perfect coalescing vs the old
// 64B/lane stride). dtp's 4 k-splits land one per lane and are reduced with
// two shfl_xor; softplus computed redundantly per quad (cheap).
// grid (10 d-chunks of 512, 256 b) = 2560 blocks, 2 barriers total.
__global__ __launch_bounds__(256) void k_epi(const float* __restrict__ x,
                                             const float* __restrict__ h0,
                                             const float* __restrict__ dtp,
                                             const float* __restrict__ bdt,
                                             const float* __restrict__ tmp,
                                             const float* __restrict__ negA,
                                             float* __restrict__ out) {
    __shared__ float bc[32];       // Bm [0..15], Cm [16..31] for this b
    const int tid = threadIdx.x;
    const int b     = blockIdx.y;
    const int dbase = blockIdx.x * 512;
    if (tid < 32) bc[tid] = tmp[(size_t)b * CT + RR + tid];
    __syncthreads();

    const int g = tid >> 2;        // quad id within block (0..63)
    const int q = tid & 3;         // lane within quad = n-group = k-split id
    const float4 bm4 = *(const float4*)&bc[q * 4];
    const float4 cm4 = *(const float4*)&bc[16 + q * 4];

    #pragma unroll 2
    for (int cc = 0; cc < 8; ++cc) {
        const int d = dbase + cc * 64 + g;
        const size_t cell = (size_t)b * DD + d;

        // dt: lane q holds k-split q; butterfly sum across the quad
        float ps = dtp[(size_t)q * BB * DD + cell];
        ps += __shfl_xor(ps, 1);
        ps += __shfl_xor(ps, 2);
        const float z  = ps + bdt[d];                               // quad-uniform
        const float dt = fmaxf(z, 0.f) + log1pf(__expf(-fabsf(z))); // softplus

        const float xe  = x[cell];                                  // quad-uniform
        const float dtx = dt * xe;
        const float4 an = *(const float4*)&negA[(size_t)d * NN + q * 4];  // coalesced
        const float4 hv = *(const float4*)&h0[cell * NN + q * 4];         // coalesced

        float r;
        {
            const float h0v = fmaf(__expf(an.x * dt), hv.x, dtx * bm4.x);
            const float h1v = fmaf(__expf(an.y * dt), hv.y, dtx * bm4.y);
            const float h2v = fmaf(__expf(an.z * dt), hv.z, dtx * bm4.z);
            const float h3v = fmaf(__expf(an.w * dt), hv.w, dtx * bm4.w);
            r = (h0v * cm4.x + h1v * cm4.y) + (h2v * cm4.z + h3v * cm4.w);
        }
        r += __shfl_xor(r, 1);
        r += __shfl_xor(r, 2);
        if (q == 0) out[cell] = r + xe;
    }
}

extern "C" void kernel_launch(void* const* d_in, const int* in_sizes, int n_in,
                              void* d_out, int out_size, void* d_ws, size_t ws_size,
                              hipStream_t stream) {
    const float* x    = (const float*)d_in[0];
    const float* h0   = (const float*)d_in[1];
    const float* Wxdt = (const float*)d_in[2];
    const float* Wdt  = (const float*)d_in[3];
    const float* bdt  = (const float*)d_in[4];
    const float* Wbc  = (const float*)d_in[5];
    const float* Alog = (const float*)d_in[6];
    float* out = (float*)d_out;

    // ws layout (floats): part[32*49152] | tmp[49152] | negA[81920] | dtp[4*BB*DD]
    float* part = (float*)d_ws;
    float* tmp  = part + (size_t)NSPLIT * TMP_ELEMS;
    float* negA = tmp + TMP_ELEMS;
    float* dtp  = negA + NEGA_ELEMS;

    k1_gemm<<<dim3(3, 4, NSPLIT), 256, 0, stream>>>(x, Wxdt, Wbc, part);
    k_red<<<dim3((TMP_ELEMS + NEGA_ELEMS) / 256), 256, 0, stream>>>(part, Alog, tmp, negA);
    k_dt<<<dim3(DD / 64, BB / 64, DTSPLIT), 256, 0, stream>>>(tmp, Wdt, dtp);
    k_epi<<<dim3(DD / 512, BB), 256, 0, stream>>>(x, h0, dtp, bdt, tmp, negA, out);
}

// Round 12
// 174.013 us; speedup vs baseline: 1.0341x; 1.0341x over previous
//
#include <hip/hip_runtime.h>
#include <math.h>

#define BB 256
#define DD 5120
#define NN 16
#define RR 160
#define CT 192          // 160 (t) + 16 (Bm) + 16 (Cm)
#define NSPLIT 40
#define K1_KRANGE 128   // 40 * 128 = 5120
#define TMP_ELEMS (BB * CT)          // 49152
#define NEGA_ELEMS (DD * NN)         // 81920

// ---------------- K1: partials[s][b][c] = x[b, ks:ks+128] @ Wcat[ks:ks+128, c]
// Round-1 tile/micro structure, KRANGE=128: grid (3 c, 4 b, 40 ksplits) = 480
// blocks. (Exact r10 version — the one measured improvement: -2.2 us total.)
__global__ __launch_bounds__(256) void k1_gemm(const float* __restrict__ x,
                                               const float* __restrict__ Wxdt,
                                               const float* __restrict__ Wbc,
                                               float* __restrict__ part) {
    __shared__ float xs[32][68];   // [k][b] transposed (68: b128-aligned rows)
    __shared__ float ws[32][64];   // [k][c]
    const int tid = threadIdx.x;
    const int tx = tid & 15, ty = tid >> 4;
    const int c0 = blockIdx.x * 64;
    const int b0 = blockIdx.y * 64;
    const int k0 = blockIdx.z * K1_KRANGE;
    float acc[4][4] = {};

    for (int kc = 0; kc < K1_KRANGE; kc += 32) {
        {
            const int i  = tid >> 3;          // 0..31
            const int j4 = (tid & 7) * 4;     // 0..28
            #pragma unroll
            for (int rep = 0; rep < 2; ++rep) {
                const int row = i + rep * 32;
                const float4 v = *(const float4*)&x[(size_t)(b0 + row) * DD + k0 + kc + j4];
                xs[j4 + 0][row] = v.x;
                xs[j4 + 1][row] = v.y;
                xs[j4 + 2][row] = v.z;
                xs[j4 + 3][row] = v.w;
            }
        }
        {
            const int c4 = (tid & 15) * 4;
            const int r0 = tid >> 4;          // 0..15
            #pragma unroll
            for (int rep = 0; rep < 2; ++rep) {
                const int r  = r0 + rep * 16;
                const int kg = k0 + kc + r;
                const int cg = c0 + c4;
                float4 v;
                if (cg < RR) v = *(const float4*)&Wxdt[(size_t)kg * RR + cg];
                else         v = *(const float4*)&Wbc[(size_t)kg * 32 + (cg - RR)];
                *(float4*)&ws[r][c4] = v;
            }
        }
        __syncthreads();
        #pragma unroll
        for (int k = 0; k < 32; ++k) {
            const float4 a4 = *(const float4*)&xs[k][ty * 4];
            const float4 w4 = *(const float4*)&ws[k][tx * 4];
            const float av[4] = {a4.x, a4.y, a4.z, a4.w};
            const float wv[4] = {w4.x, w4.y, w4.z, w4.w};
            #pragma unroll
            for (int u = 0; u < 4; ++u)
                #pragma unroll
                for (int v = 0; v < 4; ++v)
                    acc[u][v] = fmaf(av[u], wv[v], acc[u][v]);
        }
        __syncthreads();
    }

    float* p = part + (size_t)blockIdx.z * TMP_ELEMS;
    #pragma unroll
    for (int u = 0; u < 4; ++u) {
        const int b = b0 + ty * 4 + u;
        *(float4*)&p[b * CT + c0 + tx * 4] =
            make_float4(acc[u][0], acc[u][1], acc[u][2], acc[u][3]);
    }
}

// ---------------- K_RED: tmp = sum_s partials; negA2 = -exp(A_log)*log2e ----
// negA pre-scaled by log2(e) so k_fused can use native exp2 (v_exp) with one
// mul instead of two.
__global__ __launch_bounds__(256) void k_red(const float* __restrict__ part,
                                             const float* __restrict__ Alog,
                                             float* __restrict__ tmp,
                                             float* __restrict__ negA) {
    const int idx = blockIdx.x * 256 + threadIdx.x;
    if (idx < TMP_ELEMS) {
        float s = 0.f;
        #pragma unroll
        for (int z = 0; z < NSPLIT; ++z) s += part[(size_t)z * TMP_ELEMS + idx];
        tmp[idx] = s;
    } else {
        const int j = idx - TMP_ELEMS;
        negA[j] = -__expf(Alog[j]) * 1.442695041f;   // x log2(e)
    }
}

// ---------------- K_FUSED: dt dot-product + SSM epilogue --------------------
// dt[b,d] = softplus(sum_k t[b,k]*Wdt[k,d] + bdt[d])
// y[b,d]  = sum_n exp2(negA2[d,n]*dt)*h0[b,d,n]*Cm[b,n] + dt*x*bcdot[b] + x
//   where bcdot[b] = sum_n Bm[b,n]*Cm[b,n]  (factored out of the n-loop:
//   sum_n dtx*Bm[n]*Cm[n] = dtx * bcdot — computed once per row at staging).
// Hot loop per n: mul, exp2, mul, fma = 4 ops (was 6). -33% VALU.
__global__ __launch_bounds__(256) void k_fused(const float* __restrict__ x,
                                               const float* __restrict__ h0,
                                               const float* __restrict__ Wdt,
                                               const float* __restrict__ bdt,
                                               const float* __restrict__ tmp,
                                               const float* __restrict__ negA,
                                               float* __restrict__ out) {
    __shared__ float ts[4][CT];        // 4 rows of t(160)+Bm(16)+Cm(16)
    __shared__ float bcd[4];           // per-row Bm.Cm dot
    const int tid = threadIdx.x;
    const int b0 = blockIdx.x * 4;     // fast axis: shares Wdt panel
    const int d  = blockIdx.y * 256 + tid;

    // stage 4 t/BC rows (768 floats), coalesced
    for (int p = tid; p < 4 * CT; p += 256)
        ts[p / CT][p % CT] = tmp[(size_t)b0 * CT + p];
    __syncthreads();
    if (tid < 4) {
        float s = 0.f;
        #pragma unroll
        for (int n = 0; n < NN; ++n) s += ts[tid][RR + n] * ts[tid][RR + 16 + n];
        bcd[tid] = s;
    }
    __syncthreads();

    // ---- dt dot-product: Wdt via coalesced vmem; t via ds_read_b128 ----
    const float* wcol = Wdt + d;
    float acc[4] = {0.f, 0.f, 0.f, 0.f};
    #pragma unroll 2
    for (int k8 = 0; k8 < RR; k8 += 8) {
        float w[8];
        #pragma unroll
        for (int j = 0; j < 8; ++j) w[j] = wcol[(size_t)(k8 + j) * DD];
        #pragma unroll
        for (int bi = 0; bi < 4; ++bi) {
            const float4 ta = *(const float4*)&ts[bi][k8];      // ds_read_b128
            const float4 tb = *(const float4*)&ts[bi][k8 + 4];  // ds_read_b128
            acc[bi] = fmaf(ta.x, w[0], acc[bi]);
            acc[bi] = fmaf(ta.y, w[1], acc[bi]);
            acc[bi] = fmaf(ta.z, w[2], acc[bi]);
            acc[bi] = fmaf(ta.w, w[3], acc[bi]);
            acc[bi] = fmaf(tb.x, w[4], acc[bi]);
            acc[bi] = fmaf(tb.y, w[5], acc[bi]);
            acc[bi] = fmaf(tb.z, w[6], acc[bi]);
            acc[bi] = fmaf(tb.w, w[7], acc[bi]);
        }
    }

    // negA2[d, 0..15] into registers (reused across the 4 b's)
    float av[16];
    {
        const float* ap = &negA[(size_t)d * NN];
        #pragma unroll
        for (int n4 = 0; n4 < NN; n4 += 4) {
            const float4 a4 = *(const float4*)&ap[n4];
            av[n4 + 0] = a4.x; av[n4 + 1] = a4.y;
            av[n4 + 2] = a4.z; av[n4 + 3] = a4.w;
        }
    }
    const float bdv = bdt[d];

    // ---- epilogue: softplus + SSM (factored form) ----
    #pragma unroll
    for (int bi = 0; bi < 4; ++bi) {
        const float z  = acc[bi] + bdv;
        const float dt = fmaxf(z, 0.f) + log1pf(__expf(-fabsf(z)));  // softplus
        const size_t cell = (size_t)(b0 + bi) * DD + d;
        const float xe  = x[cell];
        const float* hp = &h0[cell * NN];
        float cm[16];
        #pragma unroll
        for (int n4 = 0; n4 < NN; n4 += 4) {
            const float4 cv4 = *(const float4*)&ts[bi][RR + 16 + n4];  // b128
            cm[n4 + 0] = cv4.x; cm[n4 + 1] = cv4.y;
            cm[n4 + 2] = cv4.z; cm[n4 + 3] = cv4.w;
        }
        float acc4[4] = {0.f, 0.f, 0.f, 0.f};
        #pragma unroll
        for (int n4 = 0; n4 < NN; n4 += 4) {
            const float4 h4 = *(const float4*)&hp[n4];
            const float hv[4] = {h4.x, h4.y, h4.z, h4.w};
            #pragma unroll
            for (int q = 0; q < 4; ++q) {
                const int n = n4 + q;
                const float dA = exp2f(av[n] * dt);       // native v_exp
                acc4[q] = fmaf(dA * hv[q], cm[n], acc4[q]);
            }
        }
        const float yv = fmaf(dt * xe, bcd[bi],
                              xe + (acc4[0] + acc4[1]) + (acc4[2] + acc4[3]));
        out[cell] = yv;
    }
}

extern "C" void kernel_launch(void* const* d_in, const int* in_sizes, int n_in,
                              void* d_out, int out_size, void* d_ws, size_t ws_size,
                              hipStream_t stream) {
    const float* x    = (const float*)d_in[0];
    const float* h0   = (const float*)d_in[1];
    const float* Wxdt = (const float*)d_in[2];
    const float* Wdt  = (const float*)d_in[3];
    const float* bdt  = (const float*)d_in[4];
    const float* Wbc  = (const float*)d_in[5];
    const float* Alog = (const float*)d_in[6];
    float* out = (float*)d_out;

    // ws layout (floats): partials[40*49152] (7.9 MB) | tmp[49152] | negA[81920]
    float* part = (float*)d_ws;
    float* tmp  = part + (size_t)NSPLIT * TMP_ELEMS;
    float* negA = tmp + TMP_ELEMS;

    k1_gemm<<<dim3(3, 4, NSPLIT), 256, 0, stream>>>(x, Wxdt, Wbc, part);
    k_red<<<dim3((TMP_ELEMS + NEGA_ELEMS) / 256), 256, 0, stream>>>(part, Alog, tmp, negA);
    k_fused<<<dim3(BB / 4, DD / 256), 256, 0, stream>>>(x, h0, Wdt, bdt, tmp, negA, out);
}